// Round 5
// baseline (277.621 us; speedup 1.0000x reference)
//
#include <hip/hip_runtime.h>

#define N_SAMP 48
#define TPR 4               // threads per ray
#define ROUNDS 3            // float4-chunks per thread
#define CSZ 4               // samples per chunk (one float4 of z/sigma)
#define RPB 64              // rays per block
#define BLOCK (RPB * TPR)   // 256 threads

typedef float vf4 __attribute__((ext_vector_type(4)));

// Round-5 experiment: round-4 kernel (nt loads, chunked coalesced mapping)
// + a SINGLE asm statement that consumes all 15 float4 load results as
// inputs at one program point. Unlike the round-3 per-value pins (which the
// compiler defeated: VGPR=40), one asm requiring all 60 floats simultaneously
// forces the allocator to give every load a distinct live destination, so all
// 15 nt loads issue back-to-back with ONE s_waitcnt before compute:
// per-wave loads-in-flight 5 -> 15. Proof counter: VGPR_Count 40 -> ~96.
__global__ __launch_bounds__(BLOCK) void volrender_kernel(
    const vf4* __restrict__ rgb4,    // n_rays * 36 float4
    const vf4* __restrict__ sigma4,  // n_rays * 12 float4
    const vf4* __restrict__ z4,      // n_rays * 12 float4
    float* __restrict__ out_rgb,     // n_rays * 3 floats
    float* __restrict__ out_depth,   // n_rays floats
    int n_rays)
{
    const int t    = threadIdx.x;
    const int rl   = t >> 2;     // ray within block
    const int q    = t & 3;      // lane's chunk slot within each round
    const int ray  = blockIdx.x * RPB + rl;
    const int rayc = (ray < n_rays) ? ray : (n_rays - 1);

    float zloc[ROUNDS][CSZ];        // z of chunk (4r+q)
    float sloc[ROUNDS][CSZ];        // sigma of chunk (4r+q)
    float rloc[ROUNDS][CSZ * 3];    // rgb of chunk (4r+q)

    // ---- all 15 global nt loads issued up front ----
    {
        const size_t zb = (size_t)rayc * 12 + q;     // float4 units
#pragma unroll
        for (int r = 0; r < ROUNDS; ++r)
            *reinterpret_cast<vf4*>(zloc[r]) = __builtin_nontemporal_load(&z4[zb + 4 * r]);
#pragma unroll
        for (int r = 0; r < ROUNDS; ++r)
            *reinterpret_cast<vf4*>(sloc[r]) = __builtin_nontemporal_load(&sigma4[zb + 4 * r]);
        const size_t rb = (size_t)rayc * 36 + 3 * q; // float4 units
#pragma unroll
        for (int r = 0; r < ROUNDS; ++r)
#pragma unroll
            for (int k = 0; k < 3; ++k)
                reinterpret_cast<vf4*>(rloc[r])[k] = __builtin_nontemporal_load(&rgb4[rb + 12 * r + k]);
    }

    // ---- one asm point that needs ALL 60 floats live simultaneously ----
    asm volatile("" ::
        "v"(*reinterpret_cast<vf4*>(zloc[0])),
        "v"(*reinterpret_cast<vf4*>(zloc[1])),
        "v"(*reinterpret_cast<vf4*>(zloc[2])),
        "v"(*reinterpret_cast<vf4*>(sloc[0])),
        "v"(*reinterpret_cast<vf4*>(sloc[1])),
        "v"(*reinterpret_cast<vf4*>(sloc[2])),
        "v"(reinterpret_cast<vf4*>(rloc[0])[0]),
        "v"(reinterpret_cast<vf4*>(rloc[0])[1]),
        "v"(reinterpret_cast<vf4*>(rloc[0])[2]),
        "v"(reinterpret_cast<vf4*>(rloc[1])[0]),
        "v"(reinterpret_cast<vf4*>(rloc[1])[1]),
        "v"(reinterpret_cast<vf4*>(rloc[1])[2]),
        "v"(reinterpret_cast<vf4*>(rloc[2])[0]),
        "v"(reinterpret_cast<vf4*>(rloc[2])[1]),
        "v"(reinterpret_cast<vf4*>(rloc[2])[2])
        : "memory");
    __builtin_amdgcn_sched_barrier(0);   // loads stay above, compute below

    const int lane = t & 63;
    const int base = lane & ~3;

    // ---- z of the first sample of chunk c+1, for each of this thread's chunks
    // q<3 -> lane q+1, same round (chunk c+1); q==3 -> lane 0 of round r+1.
    float A[ROUNDS];
#pragma unroll
    for (int r = 0; r < ROUNDS; ++r)
        A[r] = __shfl(zloc[r][0], base + ((q + 1) & 3));

    // ---- per-chunk local pass: weights with chunk-local exclusive T ----
    float Q[ROUNDS];                         // chunk transmittance product
    float car[ROUNDS], cag[ROUNDS], cab[ROUNDS], cad[ROUNDS];
#pragma unroll
    for (int r = 0; r < ROUNDS; ++r) {
        const float znext = (q < 3) ? A[r] : A[(r < ROUNDS - 1) ? r + 1 : r];
        float T = 1.0f, ar = 0.0f, ag = 0.0f, ab = 0.0f, ad = 0.0f;
#pragma unroll
        for (int j = 0; j < CSZ; ++j) {
            const float zn   = (j < CSZ - 1) ? zloc[r][j + 1] : znext;
            const bool  gl   = (r == ROUNDS - 1) && (q == TPR - 1) && (j == CSZ - 1);
            const float dist = gl ? 1e10f : (zn - zloc[r][j]);
            const float alpha = 1.0f - __expf(-sloc[r][j] * dist);
            const float w     = alpha * T;
            T *= (1.0f - alpha + 1e-10f);
            ar = fmaf(w, rloc[r][3 * j + 0], ar);
            ag = fmaf(w, rloc[r][3 * j + 1], ag);
            ab = fmaf(w, rloc[r][3 * j + 2], ab);
            ad = fmaf(w, zloc[r][j], ad);
        }
        Q[r] = T;
        car[r] = ar; cag[r] = ag; cab[r] = ab; cad[r] = ad;
    }

    // ---- exclusive prefix product over the 12 chunks ----
    float pre[ROUNDS], R[ROUNDS];
#pragma unroll
    for (int r = 0; r < ROUNDS; ++r) {
        const float q0 = __shfl(Q[r], base + 0);
        const float q1 = __shfl(Q[r], base + 1);
        const float q2 = __shfl(Q[r], base + 2);
        const float q3 = __shfl(Q[r], base + 3);
        float p = 1.0f;
        if (q > 0) p *= q0;
        if (q > 1) p *= q1;
        if (q > 2) p *= q2;
        pre[r] = p;
        R[r]   = q0 * q1 * q2 * q3;
    }
    const float S0 = pre[0];
    const float S1 = R[0] * pre[1];
    const float S2 = R[0] * R[1] * pre[2];

    float ar = S0 * car[0]; ar = fmaf(S1, car[1], ar); ar = fmaf(S2, car[2], ar);
    float ag = S0 * cag[0]; ag = fmaf(S1, cag[1], ag); ag = fmaf(S2, cag[2], ag);
    float ab = S0 * cab[0]; ab = fmaf(S1, cab[1], ab); ab = fmaf(S2, cab[2], ab);
    float ad = S0 * cad[0]; ad = fmaf(S1, cad[1], ad); ad = fmaf(S2, cad[2], ad);

    // ---- reduce the 4 lanes of each ray ----
    ar += __shfl_xor(ar, 1); ag += __shfl_xor(ag, 1);
    ab += __shfl_xor(ab, 1); ad += __shfl_xor(ad, 1);
    ar += __shfl_xor(ar, 2); ag += __shfl_xor(ag, 2);
    ab += __shfl_xor(ab, 2); ad += __shfl_xor(ad, 2);

    if (q == 0 && ray < n_rays) {
        __builtin_nontemporal_store(ar, &out_rgb[(size_t)ray * 3 + 0]);
        __builtin_nontemporal_store(ag, &out_rgb[(size_t)ray * 3 + 1]);
        __builtin_nontemporal_store(ab, &out_rgb[(size_t)ray * 3 + 2]);
        __builtin_nontemporal_store(ad, &out_depth[ray]);
    }
}

extern "C" void kernel_launch(void* const* d_in, const int* in_sizes, int n_in,
                              void* d_out, int out_size, void* d_ws, size_t ws_size,
                              hipStream_t stream) {
    const vf4* rgb4   = (const vf4*)d_in[0];  // (B,HW,48,3) f32
    const vf4* sigma4 = (const vf4*)d_in[1];  // (B,HW,48,1) f32
    const vf4* z4     = (const vf4*)d_in[2];  // (B,HW,48)   f32

    const int n_rays = in_sizes[2] / N_SAMP;

    float* out_rgb   = (float*)d_out;
    float* out_depth = out_rgb + (size_t)n_rays * 3;

    const int grid = (n_rays + RPB - 1) / RPB;   // 4096 blocks for 262144 rays
    hipLaunchKernelGGL(volrender_kernel, dim3(grid), dim3(BLOCK), 0, stream,
                       rgb4, sigma4, z4, out_rgb, out_depth, n_rays);
}